// Round 2
// baseline (166.749 us; speedup 1.0000x reference)
//
#include <hip/hip_runtime.h>

#define N_NODES 50000
#define N_EDGES 800000
#define D 64
#define H 128
#define NLIVE 98       // live 512-node buckets = ceil(50000/512)
#define NSEG 3136      // 98*32 level-2 segments (16 nodes each); seg = row>>4
#define BT 2048        // edges per scatter tile
#define NBB 391        // ceil(N_EDGES/BT)
#define SCAP2 352      // csr2 slots per segment (mean 256, sigma 16, +6sigma)
#define CVB512 1595    // conversion blocks: ceil(816384/512)

typedef __attribute__((ext_vector_type(8))) short  short8;   // 8 bf16
typedef __attribute__((ext_vector_type(4))) float  floatx4;
typedef __attribute__((ext_vector_type(4))) unsigned short ushort4v;

__device__ inline unsigned short f2bf(float f) {   // round-to-nearest-even
    unsigned u = __builtin_bit_cast(unsigned, f);
    u += 0x7FFFu + ((u >> 16) & 1u);
    return (unsigned short)(u >> 16);
}
__device__ inline float bf2f(unsigned short b) {
    unsigned u = (unsigned)b << 16;
    return __builtin_bit_cast(float, u);
}

// ---------------------------------------------------------------------------
// K1' (R18): single-level scatter straight into csr2's 3136 (bucket,sub)
// segments — replaces the old K1 level-1 sort + K2 subsort + 13 MB csr
// round-trip. K3 re-sorts its segment by nl anyway, so segment-internal
// order is irrelevant; only grouping matters.
//   Phase B: LDS rank  lp = atomicAdd(&cnt[seg],1)   (2048 atomics/block
//            over ~1500 distinct bins -> near-conflict-free)
//   Phase C: rank-0 entry per seg claims a global base
//            gb = atomicAdd(&cursor2[seg], cnt[seg]) and overwrites
//            cnt[seg] with gb   (~1500 global atomics/block, batched)
//   Phase D: csr2[seg*SCAP2 + gb + lp] = (nl<<16)|col
// Blocks [NBB, NBB+CVB512) do the x->bf16 / W1/W2 transpose conversion
// (independent work, overlaps the scatter blocks' atomic stalls).
// cursor2 is zeroed by a hipMemsetAsync before this kernel.
// ---------------------------------------------------------------------------
__global__ __launch_bounds__(512) void scatter_conv(
    const int* __restrict__ row, const int* __restrict__ col,
    int* __restrict__ cursor2, int* __restrict__ csr2,
    const float* __restrict__ x, unsigned short* __restrict__ xb,
    const float* __restrict__ W1, unsigned short* __restrict__ w1t,
    const float* __restrict__ W2, unsigned short* __restrict__ w2t)
{
    int t = threadIdx.x;
    if (blockIdx.x >= NBB) {            // ---- conversion blocks ----
        int tid = (blockIdx.x - NBB) * 512 + t;
        if (tid < 800000) {                      // x quads -> bf16
            float4 v = ((const float4*)x)[tid];
            ushort4v o;
            o.x = f2bf(v.x); o.y = f2bf(v.y); o.z = f2bf(v.z); o.w = f2bf(v.w);
            ((ushort4v*)xb)[tid] = o;
        } else {
            int i = tid - 800000;
            if (i < D * H) {                     // W1[k][n] -> w1t[n*64+k]
                int k = i >> 7, n = i & 127;
                w1t[n * D + k] = f2bf(W1[i]);
            } else if (i < 2 * D * H) {          // W2[k][n] -> w2t[n*128+k]
                int j = i - D * H;
                int k = j >> 6, n = j & 63;
                w2t[n * H + k] = f2bf(W2[j]);
            }
        }
        return;
    }

    // ---- scatter blocks: 2048 edges, 4 per thread ----
    __shared__ int cnt[NSEG];                    // 12.5 KB: rank ctr -> base

    for (int i = t; i < NSEG; i += 512) cnt[i] = 0;
    __syncthreads();

    int base = blockIdx.x * BT;
    int ia = base + t, ib = ia + 512, ic = ia + 1024, id = ia + 1536;
    int ca = min(ia, N_EDGES - 1), cb = min(ib, N_EDGES - 1);
    int cc = min(ic, N_EDGES - 1), cd = min(id, N_EDGES - 1);
    unsigned ra = (unsigned)row[ca], rb = (unsigned)row[cb];
    unsigned rc = (unsigned)row[cc], rd = (unsigned)row[cd];
    unsigned ka = (unsigned)col[ca], kb = (unsigned)col[cb];
    unsigned kc = (unsigned)col[cc], kd = (unsigned)col[cd];
    bool va = ia < N_EDGES, vb = ib < N_EDGES;
    bool vc = ic < N_EDGES, vd = id < N_EDGES;
    int sa = (int)(ra >> 4), sb = (int)(rb >> 4);
    int sc = (int)(rc >> 4), sd = (int)(rd >> 4);

    int lpa = 0, lpb = 0, lpc = 0, lpd = 0;      // Phase B: LDS ranks
    if (va) lpa = atomicAdd(&cnt[sa], 1);
    if (vb) lpb = atomicAdd(&cnt[sb], 1);
    if (vc) lpc = atomicAdd(&cnt[sc], 1);
    if (vd) lpd = atomicAdd(&cnt[sd], 1);
    __syncthreads();

    // Phase C: rank-0 entries claim global bases (one batched atomic per
    // touched seg); overwrite cnt[seg] with the base.
    if (va && lpa == 0) { int c = cnt[sa];
        cnt[sa] = atomicAdd(&cursor2[sa], c); }
    if (vb && lpb == 0) { int c = cnt[sb];
        cnt[sb] = atomicAdd(&cursor2[sb], c); }
    if (vc && lpc == 0) { int c = cnt[sc];
        cnt[sc] = atomicAdd(&cursor2[sc], c); }
    if (vd && lpd == 0) { int c = cnt[sd];
        cnt[sd] = atomicAdd(&cursor2[sd], c); }
    __syncthreads();

    // Phase D: place. Entry packs (nl<<16)|col for K3.
    if (va) { int p = cnt[sa] + lpa;
        if (p < SCAP2) csr2[(size_t)sa * SCAP2 + p] = (int)(((ra & 15u) << 16) | ka); }
    if (vb) { int p = cnt[sb] + lpb;
        if (p < SCAP2) csr2[(size_t)sb * SCAP2 + p] = (int)(((rb & 15u) << 16) | kb); }
    if (vc) { int p = cnt[sc] + lpc;
        if (p < SCAP2) csr2[(size_t)sc * SCAP2 + p] = (int)(((rc & 15u) << 16) | kc); }
    if (vd) { int p = cnt[sd] + lpd;
        if (p < SCAP2) csr2[(size_t)sd * SCAP2 + p] = (int)(((rd & 15u) << 16) | kd); }
}

// ---------------------------------------------------------------------------
// K3 (unchanged): block = (bucket,sub) = 16 nodes; 3136 blocks, ~9 KB LDS,
// launch_bounds(256,8). 16-bin sort of own list, quarter-wave ushort4
// gather (one 128B line per entry, 4 entries/load-instr), shfl_xor (16,32)
// reduce, wave-0 MFMA MLP with weights from global (L1-hot).
// ---------------------------------------------------------------------------
__global__ __launch_bounds__(256, 8) void gather_mlp(
    const float* __restrict__ x, const unsigned short* __restrict__ xb,
    const int* __restrict__ cursor2, const int* __restrict__ csr2,
    const unsigned short* __restrict__ w1t, const float* __restrict__ b1,
    const unsigned short* __restrict__ w2t, const float* __restrict__ b2,
    const float* __restrict__ eps, float* __restrict__ out)
{
    __shared__ int ent[SCAP2];                   // 1.4 KB
    __shared__ unsigned short scol[SCAP2];       // 0.7 KB
    __shared__ int cnt16[16], offs[17], curs[16];
    __shared__ unsigned short HB[16][72];        // 2.3 KB
    __shared__ unsigned short HID[16][136];      // 4.4 KB (wave-0 private)

    int t = threadIdx.x, lane = t & 63, wid = t >> 6;
    int bs = blockIdx.x;
    int bucket = bs >> 5, sub = bs & 31;

    if (t < 16) cnt16[t] = 0;
    __syncthreads();

    int n2 = min(cursor2[bs], SCAP2);
    const int* src = csr2 + (size_t)bs * SCAP2;

    for (int i = t; i < n2; i += 256) {          // stage + hist in one pass
        int e = src[i];
        ent[i] = e;
        atomicAdd(&cnt16[((unsigned)e >> 16) & 15u], 1);
    }
    __syncthreads();

    if (t < 16) {                                // scan 16 bins
        int v = cnt16[t];
        int incl = v;
        #pragma unroll
        for (int d = 1; d < 16; d <<= 1) {
            int y = __shfl_up(incl, d);
            if (lane >= d) incl += y;
        }
        offs[t] = incl - v;
        curs[t] = incl - v;
        if (t == 15) offs[16] = incl;
    }
    __syncthreads();

    for (int i = t; i < n2; i += 256) {          // place (LDS only)
        int e = ent[i];
        int nl = (int)(((unsigned)e >> 16) & 15u);
        int p = atomicAdd(&curs[nl], 1);
        scol[p] = (unsigned short)(e & 0xFFFF);
    }
    __syncthreads();

    // ---- quarter-wave register gather: wave wid owns nodes wid*4..+3 ----
    float ep = 1.0f + eps[0];
    int ent4 = lane >> 4;          // entry slot 0..3 within the wave group
    int fl = lane & 15;            // feature nibble: features 4fl..4fl+3
    #pragma unroll 1
    for (int nn = 0; nn < 4; ++nn) {
        int nl = wid * 4 + nn;                   // 0..15
        int node = bucket * 512 + sub * 16 + nl;
        int jb = offs[nl], je = offs[nl + 1];
        float4 xv = {0.f, 0.f, 0.f, 0.f};        // prefetch self-term: its
        if (lane < 16 && node < N_NODES)         // latency hides under gather
            xv = *(const float4*)&x[(size_t)node * D + 4 * fl];
        float a0 = 0.f, a1 = 0.f, a2 = 0.f, a3 = 0.f;
        float b0v = 0.f, b1v = 0.f, b2v = 0.f, b3v = 0.f;
        for (int j = jb; j < je; j += 8) {
            int i0 = j + ent4, i1 = j + 4 + ent4;
            bool v0 = i0 < je, v1 = i1 < je;
            int c0 = scol[v0 ? i0 : jb];
            int c1 = scol[v1 ? i1 : jb];
            ushort4v p0 = *(const ushort4v*)&xb[c0 * D + 4 * fl];
            ushort4v p1 = *(const ushort4v*)&xb[c1 * D + 4 * fl];
            if (v0) { a0 += bf2f(p0.x); a1 += bf2f(p0.y);
                      a2 += bf2f(p0.z); a3 += bf2f(p0.w); }
            if (v1) { b0v += bf2f(p1.x); b1v += bf2f(p1.y);
                      b2v += bf2f(p1.z); b3v += bf2f(p1.w); }
        }
        float s0 = a0 + b0v, s1 = a1 + b1v, s2 = a2 + b2v, s3 = a3 + b3v;
        s0 += __shfl_xor(s0, 16); s1 += __shfl_xor(s1, 16);
        s2 += __shfl_xor(s2, 16); s3 += __shfl_xor(s3, 16);
        s0 += __shfl_xor(s0, 32); s1 += __shfl_xor(s1, 32);
        s2 += __shfl_xor(s2, 32); s3 += __shfl_xor(s3, 32);
        if (lane < 16) {
            ushort4v o;
            o.x = f2bf(fmaf(ep, xv.x, s0));
            o.y = f2bf(fmaf(ep, xv.y, s1));
            o.z = f2bf(fmaf(ep, xv.z, s2));
            o.w = f2bf(fmaf(ep, xv.w, s3));
            *(ushort4v*)&HB[nl][4 * fl] = o;
        }
    }
    __syncthreads();   // HB written by all waves, read by wave 0

    // ---- MLP: wave 0 owns the 16 nodes; weights from global (L1-hot) ----
    if (wid == 0) {
        int m = lane & 15, q = lane >> 4;
        short8 a0 = *(const short8*)&HB[m][q * 8];
        short8 a1 = *(const short8*)&HB[m][32 + q * 8];

        #pragma unroll
        for (int nt = 0; nt < 8; ++nt) {
            float bias = b1[nt * 16 + m];
            floatx4 acc = {bias, bias, bias, bias};
            short8 w0 = *(const short8*)&w1t[(nt * 16 + m) * D + q * 8];
            short8 w1 = *(const short8*)&w1t[(nt * 16 + m) * D + 32 + q * 8];
            acc = __builtin_amdgcn_mfma_f32_16x16x32_bf16(a0, w0, acc, 0, 0, 0);
            acc = __builtin_amdgcn_mfma_f32_16x16x32_bf16(a1, w1, acc, 0, 0, 0);
            #pragma unroll
            for (int r = 0; r < 4; ++r) {
                float hv = fmaxf(acc[r], 0.0f);
                HID[q * 4 + r][nt * 16 + m] = f2bf(hv);
            }
        }
        // wave-internal LDS RAW: compiler inserts lgkmcnt waits; no barrier

        short8 ha[4];
        #pragma unroll
        for (int kc2 = 0; kc2 < 4; ++kc2)
            ha[kc2] = *(const short8*)&HID[m][kc2 * 32 + q * 8];

        #pragma unroll
        for (int nt2 = 0; nt2 < 4; ++nt2) {
            float bias = b2[nt2 * 16 + m];
            floatx4 acc = {bias, bias, bias, bias};
            #pragma unroll
            for (int kc2 = 0; kc2 < 4; ++kc2) {
                short8 w = *(const short8*)&w2t[(nt2 * 16 + m) * H + kc2 * 32 + q * 8];
                acc = __builtin_amdgcn_mfma_f32_16x16x32_bf16(ha[kc2], w, acc, 0, 0, 0);
            }
            #pragma unroll
            for (int r = 0; r < 4; ++r) {
                int nn2 = bucket * 512 + sub * 16 + q * 4 + r;
                if (nn2 < N_NODES) out[(size_t)nn2 * D + nt2 * 16 + m] = acc[r];
            }
        }
    }
}

// ---------------------------------------------------------------------------
extern "C" void kernel_launch(void* const* d_in, const int* in_sizes, int n_in,
                              void* d_out, int out_size, void* d_ws, size_t ws_size,
                              hipStream_t stream) {
    const float* x   = (const float*)d_in[0];
    const int*   ei  = (const int*)  d_in[1];   // [2, 800000] int32
    const float* W1  = (const float*)d_in[2];
    const float* b1  = (const float*)d_in[3];
    const float* W2  = (const float*)d_in[4];
    const float* b2  = (const float*)d_in[5];
    const float* eps = (const float*)d_in[6];
    float* out = (float*)d_out;

    // ws (~10.9 MB): xb | w1t | w2t | csr2 | cursor2
    unsigned short* xb  = (unsigned short*)d_ws;          // 3.2M bf16, 6.4 MB
    unsigned short* w1t = xb + (size_t)N_NODES * D;       // 8192
    unsigned short* w2t = w1t + D * H;                    // 8192
    int* csr2    = (int*)(w2t + D * H);                   // 3136*352, 4.42 MB
    int* cursor2 = csr2 + (size_t)NSEG * SCAP2;           // 3136

    const int* row = ei;
    const int* col = ei + N_EDGES;

    hipMemsetAsync(cursor2, 0, NSEG * sizeof(int), stream);
    scatter_conv<<<NBB + CVB512, 512, 0, stream>>>(row, col, cursor2, csr2,
                                                   x, xb, W1, w1t, W2, w2t);
    gather_mlp<<<NSEG, 256, 0, stream>>>(x, xb, cursor2, csr2,
                                         w1t, b1, w2t, b2, eps, out);
}

// Round 3
// 119.714 us; speedup vs baseline: 1.3929x; 1.3929x over previous
//
#include <hip/hip_runtime.h>

#define N_NODES 50000
#define N_EDGES 800000
#define D 64
#define H 128
#define NLIVE 98       // live 512-node buckets = ceil(50000/512)
#define NBPAD 128      // padded bin arrays for scans
#define BT 2048        // edges per level-1 tile
#define NBB 391        // ceil(N_EDGES/BT)
#define CAPT 64        // slots per (tile,bucket) segment (mean 21; 256B-aligned, /CAPT = shift)
#define NT8 49         // tiles per eighth
#define STG 1280       // K2 stage cap (mean 1020, sigma 32)
#define SCAP2 352      // csr2 slots per (bucket,sub) (mean 256, sigma 16)
#define NSUBB 784      // K2 subsort blocks (98*8)
#define CVB 3189       // conversion blocks in K2 grid: ceil(816384/256)

typedef __attribute__((ext_vector_type(8))) short  short8;   // 8 bf16
typedef __attribute__((ext_vector_type(4))) float  floatx4;
typedef __attribute__((ext_vector_type(4))) unsigned short ushort4v;

__device__ inline unsigned short f2bf(float f) {   // round-to-nearest-even
    unsigned u = __builtin_bit_cast(unsigned, f);
    u += 0x7FFFu + ((u >> 16) & 1u);
    return (unsigned short)(u >> 16);
}
__device__ inline float bf2f(unsigned short b) {
    unsigned u = (unsigned)b << 16;
    return __builtin_bit_cast(float, u);
}

// ---------------------------------------------------------------------------
// K1 (R15-proven, reverted to R1 form): LDS counting sort, 2048 entries,
// 98 live bins; fixed per-(tile,bin) segments (CAPT=64) + plain-store
// counts. Block NBB zeroes cursor2 for K2. Entry packing: (row<<16)|col.
// R18 lesson: replacing this with direct global scatter costs 4x (62 us,
// VALUBusy 1%) — coalesced segment writes are the point of this design.
// ---------------------------------------------------------------------------
__global__ __launch_bounds__(512) void bin_prep(
    const int* __restrict__ row, const int* __restrict__ col,
    int* __restrict__ counts, int* __restrict__ csr,
    int* __restrict__ cursor2)
{
    int t = threadIdx.x;
    if (blockIdx.x == NBB) {            // ---- cursor2 zeroing block ----
        for (int i = t; i < NLIVE * 32; i += 512) cursor2[i] = 0;
        return;
    }

    __shared__ int cnt[NBPAD];
    __shared__ int loffs[NBPAD];
    __shared__ int sorted[BT];      // 8 KB
    __shared__ int wsum[2];

    int lane = t & 63;
    if (t < NBPAD) cnt[t] = 0;
    __syncthreads();

    int base = blockIdx.x * BT;
    int ia = base + t, ib = ia + 512, ic = ia + 1024, id = ia + 1536;
    int ca = min(ia, N_EDGES - 1), cb = min(ib, N_EDGES - 1);
    int cc = min(ic, N_EDGES - 1), cd = min(id, N_EDGES - 1);
    unsigned ra = (unsigned)row[ca], rb = (unsigned)row[cb];
    unsigned rc = (unsigned)row[cc], rd = (unsigned)row[cd];
    unsigned ka = (unsigned)col[ca], kb = (unsigned)col[cb];
    unsigned kc = (unsigned)col[cc], kd = (unsigned)col[cd];
    bool va = ia < N_EDGES, vb = ib < N_EDGES;
    bool vc = ic < N_EDGES, vd = id < N_EDGES;
    if (va) atomicAdd(&cnt[ra >> 9], 1);
    if (vb) atomicAdd(&cnt[rb >> 9], 1);
    if (vc) atomicAdd(&cnt[rc >> 9], 1);
    if (vd) atomicAdd(&cnt[rd >> 9], 1);
    __syncthreads();

    int v = 0, incl = 0;
    if (t < NBPAD) {
        v = cnt[t];
        incl = v;
        #pragma unroll
        for (int d = 1; d < 64; d <<= 1) {
            int y = __shfl_up(incl, d);
            if (lane >= d) incl += y;
        }
        if (lane == 63) wsum[t >> 6] = incl;
    }
    __syncthreads();
    if (t < NBPAD) {
        loffs[t] = incl - v + ((t >= 64) ? wsum[0] : 0);
        if (t < NLIVE) counts[blockIdx.x * NLIVE + t] = min(v, CAPT);
    }
    __syncthreads();

    if (t < NBPAD) cnt[t] = 0;      // reuse as local cursor
    __syncthreads();

    if (va) { int b = (int)(ra >> 9); int lp = atomicAdd(&cnt[b], 1);
              sorted[loffs[b] + lp] = (int)((ra << 16) | ka); }
    if (vb) { int b = (int)(rb >> 9); int lp = atomicAdd(&cnt[b], 1);
              sorted[loffs[b] + lp] = (int)((rb << 16) | kb); }
    if (vc) { int b = (int)(rc >> 9); int lp = atomicAdd(&cnt[b], 1);
              sorted[loffs[b] + lp] = (int)((rc << 16) | kc); }
    if (vd) { int b = (int)(rd >> 9); int lp = atomicAdd(&cnt[b], 1);
              sorted[loffs[b] + lp] = (int)((rd << 16) | kd); }
    __syncthreads();

    int nloc = min(BT, N_EDGES - base);
    for (int i = t; i < nloc; i += 512) {
        unsigned en = (unsigned)sorted[i];
        int b = (int)(en >> 25);
        int rel = i - loffs[b];
        if (rel < CAPT)
            csr[((size_t)blockIdx.x * NLIVE + b) * CAPT + rel] = (int)en;
    }
}

// ---------------------------------------------------------------------------
// K2 (R17/R1 form): blocks [0,784) = (bucket, eighth) subsort via exact
// tile-prefix + binary search (100%-valid coalesced staging); blocks
// [784, 784+3189) convert x -> xb bf16 and W1/W2 -> bf16 transposed.
// ---------------------------------------------------------------------------
__global__ __launch_bounds__(256, 8) void subsort_conv(
    const int* __restrict__ counts, const int* __restrict__ csr,
    int* __restrict__ cursor2, int* __restrict__ csr2,
    const float* __restrict__ x, unsigned short* __restrict__ xb,
    const float* __restrict__ W1, unsigned short* __restrict__ w1t,
    const float* __restrict__ W2, unsigned short* __restrict__ w2t)
{
    int t = threadIdx.x;
    if (blockIdx.x >= NSUBB) {          // ---- conversion blocks ----
        int tid = (blockIdx.x - NSUBB) * 256 + t;
        if (tid < 800000) {                      // x quads -> bf16
            float4 v = ((const float4*)x)[tid];
            ushort4v o;
            o.x = f2bf(v.x); o.y = f2bf(v.y); o.z = f2bf(v.z); o.w = f2bf(v.w);
            ((ushort4v*)xb)[tid] = o;
        } else {
            int i = tid - 800000;
            if (i < D * H) {                     // W1[k][n] -> w1t[n*64+k]
                int k = i >> 7, n = i & 127;
                w1t[n * D + k] = f2bf(W1[i]);
            } else if (i < 2 * D * H) {          // W2[k][n] -> w2t[n*128+k]
                int j = i - D * H;
                int k = j >> 6, n = j & 63;
                w2t[n * H + k] = f2bf(W2[j]);
            }
        }
        return;
    }

    __shared__ int tcnt[NT8];
    __shared__ int tpref[NT8 + 1];              // exclusive prefix + total
    __shared__ int stage[STG];                  // 5 KB
    __shared__ int sorted2[STG];                // 5 KB
    __shared__ int cnt32[32], loffs[32], gbase[32], curs[32];

    int lane = t & 63;
    int bucket = blockIdx.x >> 3, q = blockIdx.x & 7;
    int tbeg = q * NT8;
    int ntile = min(NT8, NBB - tbeg);

    if (t < 32) cnt32[t] = 0;
    if (t < ntile) tcnt[t] = counts[(size_t)(tbeg + t) * NLIVE + bucket];
    __syncthreads();

    // wave 0: exclusive prefix over per-tile counts (ntile <= 49 < 64)
    if (t < 64) {
        int v = (t < ntile) ? tcnt[t] : 0;
        int incl = v;
        #pragma unroll
        for (int d = 1; d < 64; d <<= 1) {
            int y = __shfl_up(incl, d);
            if (lane >= d) incl += y;
        }
        if (t <= ntile) tpref[t] = incl - v;    // t==ntile: v=0 -> total
    }
    __syncthreads();

    int nst = min(tpref[ntile], STG);

    // compacted stage + hist: thread i -> (tile, slot) via binary search
    for (int i = t; i < nst; i += 256) {
        int lo = 0, hi = ntile;                 // tpref[lo] <= i < tpref[hi]
        #pragma unroll
        for (int it = 0; it < 6; ++it) {        // ceil(log2(49)) = 6
            int mid = (lo + hi) >> 1;
            bool ge = tpref[mid] <= i;
            lo = ge ? mid : lo;
            hi = ge ? hi : mid;
        }
        int slot = i - tpref[lo];
        int e = csr[((size_t)(tbeg + lo) * NLIVE + bucket) * CAPT + slot];
        stage[i] = e;
        atomicAdd(&cnt32[((unsigned)e >> 20) & 31u], 1);
    }
    __syncthreads();

    if (t < 32) {                                // scan 32 bins + claim bases
        int v = cnt32[t];
        int incl = v;
        #pragma unroll
        for (int d = 1; d < 32; d <<= 1) {
            int y = __shfl_up(incl, d);
            if (lane >= d) incl += y;
        }
        loffs[t] = incl - v;
        curs[t]  = incl - v;
        gbase[t] = v ? atomicAdd(&cursor2[bucket * 32 + t], v) : 0;
    }
    __syncthreads();

    for (int i = t; i < nst; i += 256) {         // place by sub
        int e = stage[i];
        int sub = (int)(((unsigned)e >> 20) & 31u);
        int p = atomicAdd(&curs[sub], 1);
        sorted2[min(p, STG - 1)] = e;
    }
    __syncthreads();

    for (int i = t; i < nst; i += 256) {         // coalesced write-out
        unsigned en = (unsigned)sorted2[i];
        int sub = (int)((en >> 20) & 31u);
        int rel = gbase[sub] + (i - loffs[sub]);
        if (rel < SCAP2)
            csr2[((size_t)bucket * 32 + sub) * SCAP2 + rel] =
                (int)(en & 0xFFFFFu);            // (nl<<16)|col
    }
}

// ---------------------------------------------------------------------------
// K3 (R19): block = (bucket,sub) = 16 nodes; 3136 blocks, ~9 KB LDS.
// Changes vs R1:
//  (a) 4-wave MLP: layer-1's 8 nt-tiles split 2/wave (each wave writes its
//      own HID column stripes), barrier, layer-2's 4 nt2-tiles split
//      1/wave (HID shared via LDS) — removes the 3/4-idle MLP tail.
//  (b) gather j-loop widened to 16 entries/iter (4 independent 8B loads
//      in flight per lane instead of 2) — one iter covers a mean-degree
//      node.
// ---------------------------------------------------------------------------
__global__ __launch_bounds__(256, 8) void gather_mlp(
    const float* __restrict__ x, const unsigned short* __restrict__ xb,
    const int* __restrict__ cursor2, const int* __restrict__ csr2,
    const unsigned short* __restrict__ w1t, const float* __restrict__ b1,
    const unsigned short* __restrict__ w2t, const float* __restrict__ b2,
    const float* __restrict__ eps, float* __restrict__ out)
{
    __shared__ int ent[SCAP2];                   // 1.4 KB
    __shared__ unsigned short scol[SCAP2];       // 0.7 KB
    __shared__ int cnt16[16], offs[17], curs[16];
    __shared__ unsigned short HB[16][72];        // 2.3 KB
    __shared__ unsigned short HID[16][136];      // 4.4 KB (now block-shared)

    int t = threadIdx.x, lane = t & 63, wid = t >> 6;
    int bs = blockIdx.x;
    int bucket = bs >> 5, sub = bs & 31;

    if (t < 16) cnt16[t] = 0;
    __syncthreads();

    int n2 = min(cursor2[bs], SCAP2);
    const int* src = csr2 + (size_t)bs * SCAP2;

    for (int i = t; i < n2; i += 256) {          // stage + hist in one pass
        int e = src[i];
        ent[i] = e;
        atomicAdd(&cnt16[((unsigned)e >> 16) & 15u], 1);
    }
    __syncthreads();

    if (t < 16) {                                // scan 16 bins
        int v = cnt16[t];
        int incl = v;
        #pragma unroll
        for (int d = 1; d < 16; d <<= 1) {
            int y = __shfl_up(incl, d);
            if (lane >= d) incl += y;
        }
        offs[t] = incl - v;
        curs[t] = incl - v;
        if (t == 15) offs[16] = incl;
    }
    __syncthreads();

    for (int i = t; i < n2; i += 256) {          // place (LDS only)
        int e = ent[i];
        int nl = (int)(((unsigned)e >> 16) & 15u);
        int p = atomicAdd(&curs[nl], 1);
        scol[p] = (unsigned short)(e & 0xFFFF);
    }
    __syncthreads();

    // ---- quarter-wave register gather: wave wid owns nodes wid*4..+3 ----
    float ep = 1.0f + eps[0];
    int ent4 = lane >> 4;          // entry slot 0..3 within the wave group
    int fl = lane & 15;            // feature nibble: features 4fl..4fl+3
    #pragma unroll 1
    for (int nn = 0; nn < 4; ++nn) {
        int nl = wid * 4 + nn;                   // 0..15
        int node = bucket * 512 + sub * 16 + nl;
        int jb = offs[nl], je = offs[nl + 1];
        float4 xv = {0.f, 0.f, 0.f, 0.f};        // prefetch self-term
        if (lane < 16 && node < N_NODES)
            xv = *(const float4*)&x[(size_t)node * D + 4 * fl];
        float a0 = 0.f, a1 = 0.f, a2 = 0.f, a3 = 0.f;
        float b0v = 0.f, b1v = 0.f, b2v = 0.f, b3v = 0.f;
        for (int j = jb; j < je; j += 16) {      // 16 entries/iter, 4 loads
            int i0 = j + ent4, i1 = i0 + 4, i2 = i0 + 8, i3 = i0 + 12;
            bool v0 = i0 < je, v1 = i1 < je, v2 = i2 < je, v3 = i3 < je;
            int cc0 = scol[v0 ? i0 : jb];
            int cc1 = scol[v1 ? i1 : jb];
            int cc2 = scol[v2 ? i2 : jb];
            int cc3 = scol[v3 ? i3 : jb];
            ushort4v p0 = *(const ushort4v*)&xb[cc0 * D + 4 * fl];
            ushort4v p1 = *(const ushort4v*)&xb[cc1 * D + 4 * fl];
            ushort4v p2 = *(const ushort4v*)&xb[cc2 * D + 4 * fl];
            ushort4v p3 = *(const ushort4v*)&xb[cc3 * D + 4 * fl];
            if (v0) { a0 += bf2f(p0.x); a1 += bf2f(p0.y);
                      a2 += bf2f(p0.z); a3 += bf2f(p0.w); }
            if (v1) { b0v += bf2f(p1.x); b1v += bf2f(p1.y);
                      b2v += bf2f(p1.z); b3v += bf2f(p1.w); }
            if (v2) { a0 += bf2f(p2.x); a1 += bf2f(p2.y);
                      a2 += bf2f(p2.z); a3 += bf2f(p2.w); }
            if (v3) { b0v += bf2f(p3.x); b1v += bf2f(p3.y);
                      b2v += bf2f(p3.z); b3v += bf2f(p3.w); }
        }
        float s0 = a0 + b0v, s1 = a1 + b1v, s2 = a2 + b2v, s3 = a3 + b3v;
        s0 += __shfl_xor(s0, 16); s1 += __shfl_xor(s1, 16);
        s2 += __shfl_xor(s2, 16); s3 += __shfl_xor(s3, 16);
        s0 += __shfl_xor(s0, 32); s1 += __shfl_xor(s1, 32);
        s2 += __shfl_xor(s2, 32); s3 += __shfl_xor(s3, 32);
        if (lane < 16) {
            ushort4v o;
            o.x = f2bf(fmaf(ep, xv.x, s0));
            o.y = f2bf(fmaf(ep, xv.y, s1));
            o.z = f2bf(fmaf(ep, xv.z, s2));
            o.w = f2bf(fmaf(ep, xv.w, s3));
            *(ushort4v*)&HB[nl][4 * fl] = o;
        }
    }
    __syncthreads();   // HB complete; read by all waves below

    // ---- MLP layer 1: 8 nt-tiles split 2 per wave ----
    {
        int m = lane & 15, q = lane >> 4;
        short8 a0 = *(const short8*)&HB[m][q * 8];
        short8 a1 = *(const short8*)&HB[m][32 + q * 8];

        #pragma unroll
        for (int u = 0; u < 2; ++u) {
            int nt = wid * 2 + u;
            float bias = b1[nt * 16 + m];
            floatx4 acc = {bias, bias, bias, bias};
            short8 w0 = *(const short8*)&w1t[(nt * 16 + m) * D + q * 8];
            short8 w1 = *(const short8*)&w1t[(nt * 16 + m) * D + 32 + q * 8];
            acc = __builtin_amdgcn_mfma_f32_16x16x32_bf16(a0, w0, acc, 0, 0, 0);
            acc = __builtin_amdgcn_mfma_f32_16x16x32_bf16(a1, w1, acc, 0, 0, 0);
            #pragma unroll
            for (int r = 0; r < 4; ++r) {
                float hv = fmaxf(acc[r], 0.0f);
                HID[q * 4 + r][nt * 16 + m] = f2bf(hv);
            }
        }
    }
    __syncthreads();   // HID column stripes from all waves

    // ---- MLP layer 2: 4 nt2-tiles split 1 per wave ----
    {
        int m = lane & 15, q = lane >> 4;
        short8 ha[4];
        #pragma unroll
        for (int kc2 = 0; kc2 < 4; ++kc2)
            ha[kc2] = *(const short8*)&HID[m][kc2 * 32 + q * 8];

        int nt2 = wid;
        float bias = b2[nt2 * 16 + m];
        floatx4 acc = {bias, bias, bias, bias};
        #pragma unroll
        for (int kc2 = 0; kc2 < 4; ++kc2) {
            short8 w = *(const short8*)&w2t[(nt2 * 16 + m) * H + kc2 * 32 + q * 8];
            acc = __builtin_amdgcn_mfma_f32_16x16x32_bf16(ha[kc2], w, acc, 0, 0, 0);
        }
        #pragma unroll
        for (int r = 0; r < 4; ++r) {
            int nn2 = bucket * 512 + sub * 16 + q * 4 + r;
            if (nn2 < N_NODES) out[(size_t)nn2 * D + nt2 * 16 + m] = acc[r];
        }
    }
}

// ---------------------------------------------------------------------------
extern "C" void kernel_launch(void* const* d_in, const int* in_sizes, int n_in,
                              void* d_out, int out_size, void* d_ws, size_t ws_size,
                              hipStream_t stream) {
    const float* x   = (const float*)d_in[0];
    const int*   ei  = (const int*)  d_in[1];   // [2, 800000] int32
    const float* W1  = (const float*)d_in[2];
    const float* b1  = (const float*)d_in[3];
    const float* W2  = (const float*)d_in[4];
    const float* b2  = (const float*)d_in[5];
    const float* eps = (const float*)d_in[6];
    float* out = (float*)d_out;

    // ws (~20.9 MB): xb | w1t | w2t | csr(segments) | counts | csr2 | cursor2
    unsigned short* xb  = (unsigned short*)d_ws;          // 3.2M bf16, 6.4 MB
    unsigned short* w1t = xb + (size_t)N_NODES * D;       // 8192
    unsigned short* w2t = w1t + D * H;                    // 8192
    int* csr     = (int*)(w2t + D * H);                   // 391*98*64, 9.8 MB
    int* counts  = csr + (size_t)NBB * NLIVE * CAPT;      // 391*98, 153 KB
    int* csr2    = counts + (size_t)NBB * NLIVE;          // 3136*352, 4.42 MB
    int* cursor2 = csr2 + (size_t)NLIVE * 32 * SCAP2;     // 3136

    const int* row = ei;
    const int* col = ei + N_EDGES;

    bin_prep<<<NBB + 1, 512, 0, stream>>>(row, col, counts, csr, cursor2);
    subsort_conv<<<NSUBB + CVB, 256, 0, stream>>>(counts, csr, cursor2, csr2,
                                                  x, xb, W1, w1t, W2, w2t);
    gather_mlp<<<NLIVE * 32, 256, 0, stream>>>(x, xb, cursor2, csr2,
                                               w1t, b1, w2t, b2, eps, out);
}

// Round 4
// 116.896 us; speedup vs baseline: 1.4265x; 1.0241x over previous
//
#include <hip/hip_runtime.h>

#define N_NODES 50000
#define N_EDGES 800000
#define D 64
#define H 128
#define NLIVE 98       // live 512-node buckets = ceil(50000/512)
#define NBPAD 128      // padded bin arrays for scans
#define BT 2048        // edges per level-1 tile
#define NBB 391        // ceil(N_EDGES/BT)
#define CAPT 64        // slots per (tile,bucket) segment (mean 21; 256B-aligned)
#define NT8 49         // tiles per eighth
#define STG 1280       // K2 stage cap (mean 1020, sigma 32)
#define SCAP2 352      // csr2 slots per (bucket,sub) (mean 256, sigma 16)
#define NSUBB 784      // K2 subsort blocks (98*8)
#define CVB512 1595    // conversion blocks in K1 grid: ceil(816384/512)

typedef __attribute__((ext_vector_type(8))) short  short8;   // 8 bf16
typedef __attribute__((ext_vector_type(4))) float  floatx4;
typedef __attribute__((ext_vector_type(4))) unsigned short ushort4v;

__device__ inline unsigned short f2bf(float f) {   // round-to-nearest-even
    unsigned u = __builtin_bit_cast(unsigned, f);
    u += 0x7FFFu + ((u >> 16) & 1u);
    return (unsigned short)(u >> 16);
}
__device__ inline float bf2f(unsigned short b) {
    unsigned u = (unsigned)b << 16;
    return __builtin_bit_cast(float, u);
}

// ---------------------------------------------------------------------------
// K1 (R20): LDS counting sort (R15-proven) + conversion blocks folded into
// this grid. K1's sort path uses only 392 blocks (1.5/CU, half the machine
// idle in round 2); the 1595 conversion blocks (x->bf16, W1/W2 transpose,
// ~19MB pure BW, no deps) fill the idle CUs instead of serializing inside
// K2's window. Block NBB zeroes cursor2. Entry packing: (row<<16)|col.
// R18 lesson: direct global scatter costs 4x — coalesced segment writes
// are the point of the two-level design.
// ---------------------------------------------------------------------------
__global__ __launch_bounds__(512) void bin_prep_conv(
    const int* __restrict__ row, const int* __restrict__ col,
    int* __restrict__ counts, int* __restrict__ csr,
    int* __restrict__ cursor2,
    const float* __restrict__ x, unsigned short* __restrict__ xb,
    const float* __restrict__ W1, unsigned short* __restrict__ w1t,
    const float* __restrict__ W2, unsigned short* __restrict__ w2t)
{
    int t = threadIdx.x;
    if (blockIdx.x == NBB) {            // ---- cursor2 zeroing block ----
        for (int i = t; i < NLIVE * 32; i += 512) cursor2[i] = 0;
        return;
    }
    if (blockIdx.x > NBB) {             // ---- conversion blocks ----
        int tid = (blockIdx.x - NBB - 1) * 512 + t;
        if (tid < 800000) {                      // x quads -> bf16
            float4 v = ((const float4*)x)[tid];
            ushort4v o;
            o.x = f2bf(v.x); o.y = f2bf(v.y); o.z = f2bf(v.z); o.w = f2bf(v.w);
            ((ushort4v*)xb)[tid] = o;
        } else {
            int i = tid - 800000;
            if (i < D * H) {                     // W1[k][n] -> w1t[n*64+k]
                int k = i >> 7, n = i & 127;
                w1t[n * D + k] = f2bf(W1[i]);
            } else if (i < 2 * D * H) {          // W2[k][n] -> w2t[n*128+k]
                int j = i - D * H;
                int k = j >> 6, n = j & 63;
                w2t[n * H + k] = f2bf(W2[j]);
            }
        }
        return;
    }

    // ---- tile blocks: LDS counting sort, 2048 entries, 98 live bins ----
    __shared__ int cnt[NBPAD];
    __shared__ int loffs[NBPAD];
    __shared__ int sorted[BT];      // 8 KB
    __shared__ int wsum[2];

    int lane = t & 63;
    if (t < NBPAD) cnt[t] = 0;
    __syncthreads();

    int base = blockIdx.x * BT;
    int ia = base + t, ib = ia + 512, ic = ia + 1024, id = ia + 1536;
    int ca = min(ia, N_EDGES - 1), cb = min(ib, N_EDGES - 1);
    int cc = min(ic, N_EDGES - 1), cd = min(id, N_EDGES - 1);
    unsigned ra = (unsigned)row[ca], rb = (unsigned)row[cb];
    unsigned rc = (unsigned)row[cc], rd = (unsigned)row[cd];
    unsigned ka = (unsigned)col[ca], kb = (unsigned)col[cb];
    unsigned kc = (unsigned)col[cc], kd = (unsigned)col[cd];
    bool va = ia < N_EDGES, vb = ib < N_EDGES;
    bool vc = ic < N_EDGES, vd = id < N_EDGES;
    if (va) atomicAdd(&cnt[ra >> 9], 1);
    if (vb) atomicAdd(&cnt[rb >> 9], 1);
    if (vc) atomicAdd(&cnt[rc >> 9], 1);
    if (vd) atomicAdd(&cnt[rd >> 9], 1);
    __syncthreads();

    int v = 0, incl = 0;
    if (t < NBPAD) {
        v = cnt[t];
        incl = v;
        #pragma unroll
        for (int d = 1; d < 64; d <<= 1) {
            int y = __shfl_up(incl, d);
            if (lane >= d) incl += y;
        }
        if (lane == 63) wsum[t >> 6] = incl;
    }
    __syncthreads();
    if (t < NBPAD) {
        loffs[t] = incl - v + ((t >= 64) ? wsum[0] : 0);
        if (t < NLIVE) counts[blockIdx.x * NLIVE + t] = min(v, CAPT);
    }
    __syncthreads();

    if (t < NBPAD) cnt[t] = 0;      // reuse as local cursor
    __syncthreads();

    if (va) { int b = (int)(ra >> 9); int lp = atomicAdd(&cnt[b], 1);
              sorted[loffs[b] + lp] = (int)((ra << 16) | ka); }
    if (vb) { int b = (int)(rb >> 9); int lp = atomicAdd(&cnt[b], 1);
              sorted[loffs[b] + lp] = (int)((rb << 16) | kb); }
    if (vc) { int b = (int)(rc >> 9); int lp = atomicAdd(&cnt[b], 1);
              sorted[loffs[b] + lp] = (int)((rc << 16) | kc); }
    if (vd) { int b = (int)(rd >> 9); int lp = atomicAdd(&cnt[b], 1);
              sorted[loffs[b] + lp] = (int)((rd << 16) | kd); }
    __syncthreads();

    int nloc = min(BT, N_EDGES - base);
    for (int i = t; i < nloc; i += 512) {
        unsigned en = (unsigned)sorted[i];
        int b = (int)(en >> 25);
        int rel = i - loffs[b];
        if (rel < CAPT)
            csr[((size_t)blockIdx.x * NLIVE + b) * CAPT + rel] = (int)en;
    }
}

// ---------------------------------------------------------------------------
// K2 (R20): subsort only — 784 blocks = (bucket, eighth). Exact tile-prefix
// + binary search staging (100%-valid coalesced loads), 32-bin scan, place,
// coalesced write-out. Conversion work moved to K1's grid.
// ---------------------------------------------------------------------------
__global__ __launch_bounds__(256, 8) void subsort(
    const int* __restrict__ counts, const int* __restrict__ csr,
    int* __restrict__ cursor2, int* __restrict__ csr2)
{
    __shared__ int tcnt[NT8];
    __shared__ int tpref[NT8 + 1];              // exclusive prefix + total
    __shared__ int stage[STG];                  // 5 KB
    __shared__ int sorted2[STG];                // 5 KB
    __shared__ int cnt32[32], loffs[32], gbase[32], curs[32];

    int t = threadIdx.x;
    int lane = t & 63;
    int bucket = blockIdx.x >> 3, q = blockIdx.x & 7;
    int tbeg = q * NT8;
    int ntile = min(NT8, NBB - tbeg);

    if (t < 32) cnt32[t] = 0;
    if (t < ntile) tcnt[t] = counts[(size_t)(tbeg + t) * NLIVE + bucket];
    __syncthreads();

    // wave 0: exclusive prefix over per-tile counts (ntile <= 49 < 64)
    if (t < 64) {
        int v = (t < ntile) ? tcnt[t] : 0;
        int incl = v;
        #pragma unroll
        for (int d = 1; d < 64; d <<= 1) {
            int y = __shfl_up(incl, d);
            if (lane >= d) incl += y;
        }
        if (t <= ntile) tpref[t] = incl - v;    // t==ntile: v=0 -> total
    }
    __syncthreads();

    int nst = min(tpref[ntile], STG);

    // compacted stage + hist: thread i -> (tile, slot) via binary search
    for (int i = t; i < nst; i += 256) {
        int lo = 0, hi = ntile;                 // tpref[lo] <= i < tpref[hi]
        #pragma unroll
        for (int it = 0; it < 6; ++it) {        // ceil(log2(49)) = 6
            int mid = (lo + hi) >> 1;
            bool ge = tpref[mid] <= i;
            lo = ge ? mid : lo;
            hi = ge ? hi : mid;
        }
        int slot = i - tpref[lo];
        int e = csr[((size_t)(tbeg + lo) * NLIVE + bucket) * CAPT + slot];
        stage[i] = e;
        atomicAdd(&cnt32[((unsigned)e >> 20) & 31u], 1);
    }
    __syncthreads();

    if (t < 32) {                                // scan 32 bins + claim bases
        int v = cnt32[t];
        int incl = v;
        #pragma unroll
        for (int d = 1; d < 32; d <<= 1) {
            int y = __shfl_up(incl, d);
            if (lane >= d) incl += y;
        }
        loffs[t] = incl - v;
        curs[t]  = incl - v;
        gbase[t] = v ? atomicAdd(&cursor2[bucket * 32 + t], v) : 0;
    }
    __syncthreads();

    for (int i = t; i < nst; i += 256) {         // place by sub
        int e = stage[i];
        int sub = (int)(((unsigned)e >> 20) & 31u);
        int p = atomicAdd(&curs[sub], 1);
        sorted2[min(p, STG - 1)] = e;
    }
    __syncthreads();

    for (int i = t; i < nst; i += 256) {         // coalesced write-out
        unsigned en = (unsigned)sorted2[i];
        int sub = (int)((en >> 20) & 31u);
        int rel = gbase[sub] + (i - loffs[sub]);
        if (rel < SCAP2)
            csr2[((size_t)bucket * 32 + sub) * SCAP2 + rel] =
                (int)(en & 0xFFFFFu);            // (nl<<16)|col
    }
}

// ---------------------------------------------------------------------------
// K3 (R20): block = (bucket,sub) = 16 nodes; 3136 blocks, ~7.6 KB LDS.
// Changes vs R19: ent[] staging deleted — hist from the coalesced global
// read, place phase re-reads csr2 (L2-hot) instead of bouncing every entry
// through LDS twice. Keeps R19's 4-wave MLP split + 16-wide gather.
// ---------------------------------------------------------------------------
__global__ __launch_bounds__(256, 8) void gather_mlp(
    const float* __restrict__ x, const unsigned short* __restrict__ xb,
    const int* __restrict__ cursor2, const int* __restrict__ csr2,
    const unsigned short* __restrict__ w1t, const float* __restrict__ b1,
    const unsigned short* __restrict__ w2t, const float* __restrict__ b2,
    const float* __restrict__ eps, float* __restrict__ out)
{
    __shared__ unsigned short scol[SCAP2];       // 0.7 KB
    __shared__ int cnt16[16], offs[17], curs[16];
    __shared__ unsigned short HB[16][72];        // 2.3 KB
    __shared__ unsigned short HID[16][136];      // 4.4 KB (block-shared)

    int t = threadIdx.x, lane = t & 63, wid = t >> 6;
    int bs = blockIdx.x;
    int bucket = bs >> 5, sub = bs & 31;

    if (t < 16) cnt16[t] = 0;
    __syncthreads();

    int n2 = min(cursor2[bs], SCAP2);
    const int* src = csr2 + (size_t)bs * SCAP2;

    for (int i = t; i < n2; i += 256)            // hist (coalesced read)
        atomicAdd(&cnt16[((unsigned)src[i] >> 16) & 15u], 1);
    __syncthreads();

    if (t < 16) {                                // scan 16 bins
        int v = cnt16[t];
        int incl = v;
        #pragma unroll
        for (int d = 1; d < 16; d <<= 1) {
            int y = __shfl_up(incl, d);
            if (lane >= d) incl += y;
        }
        offs[t] = incl - v;
        curs[t] = incl - v;
        if (t == 15) offs[16] = incl;
    }
    __syncthreads();

    for (int i = t; i < n2; i += 256) {          // place (re-read, L2-hot)
        int e = src[i];
        int nl = (int)(((unsigned)e >> 16) & 15u);
        int p = atomicAdd(&curs[nl], 1);
        scol[p] = (unsigned short)(e & 0xFFFF);
    }
    __syncthreads();

    // ---- quarter-wave register gather: wave wid owns nodes wid*4..+3 ----
    float ep = 1.0f + eps[0];
    int ent4 = lane >> 4;          // entry slot 0..3 within the wave group
    int fl = lane & 15;            // feature nibble: features 4fl..4fl+3
    #pragma unroll 1
    for (int nn = 0; nn < 4; ++nn) {
        int nl = wid * 4 + nn;                   // 0..15
        int node = bucket * 512 + sub * 16 + nl;
        int jb = offs[nl], je = offs[nl + 1];
        float4 xv = {0.f, 0.f, 0.f, 0.f};        // prefetch self-term
        if (lane < 16 && node < N_NODES)
            xv = *(const float4*)&x[(size_t)node * D + 4 * fl];
        float a0 = 0.f, a1 = 0.f, a2 = 0.f, a3 = 0.f;
        float b0v = 0.f, b1v = 0.f, b2v = 0.f, b3v = 0.f;
        for (int j = jb; j < je; j += 16) {      // 16 entries/iter, 4 loads
            int i0 = j + ent4, i1 = i0 + 4, i2 = i0 + 8, i3 = i0 + 12;
            bool v0 = i0 < je, v1 = i1 < je, v2 = i2 < je, v3 = i3 < je;
            int cc0 = scol[v0 ? i0 : jb];
            int cc1 = scol[v1 ? i1 : jb];
            int cc2 = scol[v2 ? i2 : jb];
            int cc3 = scol[v3 ? i3 : jb];
            ushort4v p0 = *(const ushort4v*)&xb[cc0 * D + 4 * fl];
            ushort4v p1 = *(const ushort4v*)&xb[cc1 * D + 4 * fl];
            ushort4v p2 = *(const ushort4v*)&xb[cc2 * D + 4 * fl];
            ushort4v p3 = *(const ushort4v*)&xb[cc3 * D + 4 * fl];
            if (v0) { a0 += bf2f(p0.x); a1 += bf2f(p0.y);
                      a2 += bf2f(p0.z); a3 += bf2f(p0.w); }
            if (v1) { b0v += bf2f(p1.x); b1v += bf2f(p1.y);
                      b2v += bf2f(p1.z); b3v += bf2f(p1.w); }
            if (v2) { a0 += bf2f(p2.x); a1 += bf2f(p2.y);
                      a2 += bf2f(p2.z); a3 += bf2f(p2.w); }
            if (v3) { b0v += bf2f(p3.x); b1v += bf2f(p3.y);
                      b2v += bf2f(p3.z); b3v += bf2f(p3.w); }
        }
        float s0 = a0 + b0v, s1 = a1 + b1v, s2 = a2 + b2v, s3 = a3 + b3v;
        s0 += __shfl_xor(s0, 16); s1 += __shfl_xor(s1, 16);
        s2 += __shfl_xor(s2, 16); s3 += __shfl_xor(s3, 16);
        s0 += __shfl_xor(s0, 32); s1 += __shfl_xor(s1, 32);
        s2 += __shfl_xor(s2, 32); s3 += __shfl_xor(s3, 32);
        if (lane < 16) {
            ushort4v o;
            o.x = f2bf(fmaf(ep, xv.x, s0));
            o.y = f2bf(fmaf(ep, xv.y, s1));
            o.z = f2bf(fmaf(ep, xv.z, s2));
            o.w = f2bf(fmaf(ep, xv.w, s3));
            *(ushort4v*)&HB[nl][4 * fl] = o;
        }
    }
    __syncthreads();   // HB complete; read by all waves below

    // ---- MLP layer 1: 8 nt-tiles split 2 per wave ----
    {
        int m = lane & 15, q = lane >> 4;
        short8 a0 = *(const short8*)&HB[m][q * 8];
        short8 a1 = *(const short8*)&HB[m][32 + q * 8];

        #pragma unroll
        for (int u = 0; u < 2; ++u) {
            int nt = wid * 2 + u;
            float bias = b1[nt * 16 + m];
            floatx4 acc = {bias, bias, bias, bias};
            short8 w0 = *(const short8*)&w1t[(nt * 16 + m) * D + q * 8];
            short8 w1 = *(const short8*)&w1t[(nt * 16 + m) * D + 32 + q * 8];
            acc = __builtin_amdgcn_mfma_f32_16x16x32_bf16(a0, w0, acc, 0, 0, 0);
            acc = __builtin_amdgcn_mfma_f32_16x16x32_bf16(a1, w1, acc, 0, 0, 0);
            #pragma unroll
            for (int r = 0; r < 4; ++r) {
                float hv = fmaxf(acc[r], 0.0f);
                HID[q * 4 + r][nt * 16 + m] = f2bf(hv);
            }
        }
    }
    __syncthreads();   // HID column stripes from all waves

    // ---- MLP layer 2: 4 nt2-tiles split 1 per wave ----
    {
        int m = lane & 15, q = lane >> 4;
        short8 ha[4];
        #pragma unroll
        for (int kc2 = 0; kc2 < 4; ++kc2)
            ha[kc2] = *(const short8*)&HID[m][kc2 * 32 + q * 8];

        int nt2 = wid;
        float bias = b2[nt2 * 16 + m];
        floatx4 acc = {bias, bias, bias, bias};
        #pragma unroll
        for (int kc2 = 0; kc2 < 4; ++kc2) {
            short8 w = *(const short8*)&w2t[(nt2 * 16 + m) * H + kc2 * 32 + q * 8];
            acc = __builtin_amdgcn_mfma_f32_16x16x32_bf16(ha[kc2], w, acc, 0, 0, 0);
        }
        #pragma unroll
        for (int r = 0; r < 4; ++r) {
            int nn2 = bucket * 512 + sub * 16 + q * 4 + r;
            if (nn2 < N_NODES) out[(size_t)nn2 * D + nt2 * 16 + m] = acc[r];
        }
    }
}

// ---------------------------------------------------------------------------
extern "C" void kernel_launch(void* const* d_in, const int* in_sizes, int n_in,
                              void* d_out, int out_size, void* d_ws, size_t ws_size,
                              hipStream_t stream) {
    const float* x   = (const float*)d_in[0];
    const int*   ei  = (const int*)  d_in[1];   // [2, 800000] int32
    const float* W1  = (const float*)d_in[2];
    const float* b1  = (const float*)d_in[3];
    const float* W2  = (const float*)d_in[4];
    const float* b2  = (const float*)d_in[5];
    const float* eps = (const float*)d_in[6];
    float* out = (float*)d_out;

    // ws (~20.9 MB): xb | w1t | w2t | csr(segments) | counts | csr2 | cursor2
    unsigned short* xb  = (unsigned short*)d_ws;          // 3.2M bf16, 6.4 MB
    unsigned short* w1t = xb + (size_t)N_NODES * D;       // 8192
    unsigned short* w2t = w1t + D * H;                    // 8192
    int* csr     = (int*)(w2t + D * H);                   // 391*98*64, 9.8 MB
    int* counts  = csr + (size_t)NBB * NLIVE * CAPT;      // 391*98, 153 KB
    int* csr2    = counts + (size_t)NBB * NLIVE;          // 3136*352, 4.42 MB
    int* cursor2 = csr2 + (size_t)NLIVE * 32 * SCAP2;     // 3136

    const int* row = ei;
    const int* col = ei + N_EDGES;

    bin_prep_conv<<<NBB + 1 + CVB512, 512, 0, stream>>>(row, col, counts, csr,
                                                        cursor2, x, xb,
                                                        W1, w1t, W2, w2t);
    subsort<<<NSUBB, 256, 0, stream>>>(counts, csr, cursor2, csr2);
    gather_mlp<<<NLIVE * 32, 256, 0, stream>>>(x, xb, cursor2, csr2,
                                               w1t, b1, w2t, b2, eps, out);
}